// Round 8
// baseline (241.576 us; speedup 1.0000x reference)
//
#include <hip/hip_runtime.h>
#include <float.h>
#include <math.h>

// NPairLoss MI355X r15 (= r14 with deterministic class-partition fix).
// TWO kernels:
//  prep : bf16 convert + sq | class blocks (8 per class, partitioned by row&7): build list +
//         wave-per-member gumbel argmax (order-independent: strict tie-break on smaller j)
//  fused: SWAPPED-OPERAND dual-A MFMA (C/D rows=j, cols=i -> lse state 4 regs, i-data resident),
//         BJ=32, chunked [kc][32][64] LDS (r9's 0-conflict layout), 2x16KB ping-pong with
//         counted vmcnt(4), 1024 blocks = exactly 4 blocks/CU one clean round,
//         last-block folds the finale reduction.
// Lessons: r10 no launch_bounds min-waves cap; r12 B via global_load_lds only; r13 136 regs = tail;
//          r14 list-position partition across atomicAdd-permuted lists = non-coverage bug.

#define B_N 8192
#define D_K 256
#define NCLS 100
#define MAXC 512
#define CPAR 8
#define NSPLIT 16
#define NPART NSPLIT
#define JR (B_N / NSPLIT)      // 512
#define BI 128
#define BJ 32
#define NJT (JR / BJ)          // 16
#define TOTB ((B_N / BI) * NSPLIT)   // 1024 fused blocks
#define NEG_INF -1e30f
#define C2F  (-14.426950408889634f)   // -10/T * log2(e)  (T=0.1)
#define K2A  (28.853900817779268f)    // +20 * log2(e)
#define LN2F (0.6931471805599453f)

typedef __attribute__((ext_vector_type(8))) short bf16x8;
typedef __attribute__((ext_vector_type(4))) float f32x4;
typedef unsigned short ushort_t;

__device__ __forceinline__ float ex2(float x){ return __builtin_amdgcn_exp2f(x); }
__device__ __forceinline__ float lg2(float x){ return __builtin_amdgcn_logf(x); }

// ---------------- threefry2x32 / jax gumbel (bit-exact, known-good) ----------------
__device__ __forceinline__ unsigned rotl32(unsigned x, int d){ return (x << d) | (x >> (32 - d)); }

__device__ __forceinline__ float gumbel_at(unsigned idx){
  const unsigned HALF = (unsigned)B_N * (unsigned)B_N / 2u;
  unsigned c0, c1; bool second;
  if (idx < HALF){ c0 = idx; c1 = idx + HALF; second = false; }
  else            { c0 = idx - HALF; c1 = idx; second = true; }
  const unsigned ks0 = 0u, ks1 = 42u, ks2 = 0u ^ 42u ^ 0x1BD11BDAu;
  unsigned x0 = c0 + ks0, x1 = c1 + ks1;
#define TF_RND(r) { x0 += x1; x1 = rotl32(x1, (r)); x1 ^= x0; }
  TF_RND(13) TF_RND(15) TF_RND(26) TF_RND(6)   x0 += ks1; x1 += ks2 + 1u;
  TF_RND(17) TF_RND(29) TF_RND(16) TF_RND(24)  x0 += ks2; x1 += ks0 + 2u;
  TF_RND(13) TF_RND(15) TF_RND(26) TF_RND(6)   x0 += ks0; x1 += ks1 + 3u;
  TF_RND(17) TF_RND(29) TF_RND(16) TF_RND(24)  x0 += ks1; x1 += ks2 + 4u;
  TF_RND(13) TF_RND(15) TF_RND(26) TF_RND(6)   x0 += ks2; x1 += ks0 + 5u;
#undef TF_RND
  unsigned bits = second ? x1 : x0;
  float u = __uint_as_float((bits >> 9) | 0x3f800000u) - 1.0f;
  const float TINY = 1.17549435e-38f;
  u = u * (1.0f - TINY) + TINY;
  u = fmaxf(TINY, u);
  return -logf(-logf(u));
}

__device__ __forceinline__ ushort_t f2bf(float x){
  unsigned u = __float_as_uint(x);
  return (ushort_t)((u + 0x7FFFu + ((u >> 16) & 1u)) >> 16); // RNE
}

__device__ __forceinline__ void async16(const ushort_t* g, ushort_t* lds_wave_base){
  __builtin_amdgcn_global_load_lds((const __attribute__((address_space(1))) void*)g,
                                   (__attribute__((address_space(3))) void*)lds_wave_base,
                                   16, 0, 0);
}

// ---------------- node 1. prep: convert + sq; class blocks (x8, row&7 partition) ----------------
__global__ __launch_bounds__(256)
void prep_kernel(const float* __restrict__ E, ushort_t* __restrict__ Ebf,
                 float* __restrict__ sq, float* __restrict__ acc4,
                 const int* __restrict__ labels, int* __restrict__ jsel){
  __shared__ int s_list[MAXC];
  __shared__ int s_n;
  if (blockIdx.x < B_N / 4){
    if (blockIdx.x == 0 && threadIdx.x < 4) acc4[threadIdx.x] = 0.f;
    int w = threadIdx.x >> 6, lane = threadIdx.x & 63;
    int row = blockIdx.x * 4 + w;
    const float4 v = *reinterpret_cast<const float4*>(E + (size_t)row * D_K + lane * 4);
    float s = v.x*v.x + v.y*v.y + v.z*v.z + v.w*v.w;
#pragma unroll
    for (int off = 32; off > 0; off >>= 1) s += __shfl_down(s, off);
    if (lane == 0) sq[row] = s;
    ushort4 o; o.x = f2bf(v.x); o.y = f2bf(v.y); o.z = f2bf(v.z); o.w = f2bf(v.w);
    *reinterpret_cast<ushort4*>(Ebf + (size_t)row * D_K + lane * 4) = o;
  } else {
    const int cb = blockIdx.x - B_N / 4;
    const int c = cb >> 3, part = cb & 7;          // 8 blocks per class, partition by row&7
    const int tid = threadIdx.x;
    const int w = tid >> 6, lane = tid & 63;
    if (tid == 0) s_n = 0;
    __syncthreads();
    for (int t = tid; t < B_N; t += 256){
      if (labels[t] == c){
        int p = atomicAdd(&s_n, 1);
        if (p < MAXC) s_list[p] = t;
      }
    }
    __syncthreads();
    const int n = min(s_n, MAXC);
    // one WAVE per member; a block only handles member rows with (row & 7) == part.
    // Coverage is exact regardless of s_list ordering; argmax is order-independent
    // (strict tie-break: greater g, or equal g and smaller j).
    for (int m = w; m < n; m += 4){
      const int row = s_list[m];
      if ((row & 7) != part) continue;
      float gb = -FLT_MAX; int jb = -1;
      for (int t = lane; t < n; t += 64){
        int j = s_list[t];
        if (j != row){
          float g = gumbel_at(((unsigned)row << 13) + (unsigned)j);
          if (g > gb || (g == gb && (unsigned)j < (unsigned)jb)){ gb = g; jb = j; }
        }
      }
#pragma unroll
      for (int off = 32; off > 0; off >>= 1){
        float g2 = __shfl_down(gb, off);
        int   j2 = __shfl_down(jb, off);
        if (g2 > gb || (g2 == gb && (unsigned)j2 < (unsigned)jb)){ gb = g2; jb = j2; }
      }
      if (lane == 0) jsel[row] = jb;
    }
  }
}

// ---------------- node 2. fused: swapped-operand MFMA gram + online lse + last-block finale ----------------
__global__ __launch_bounds__(256)
void fused_kernel(const ushort_t* __restrict__ Ebf, const int* __restrict__ labels,
                  const float* __restrict__ sq, const int* __restrict__ jsel,
                  float* __restrict__ numer,
                  float* __restrict__ wsM, float* __restrict__ wsS,
                  float* __restrict__ acc4, float* __restrict__ out)
{
  __shared__ __align__(16) ushort_t Bs[2][4][BJ * 64];  // 2 x (4 chunks x 32 rows x 64 el) = 32 KB
  __shared__ float s_h2j[JR];   // 2 KB  (= C2F * sq[j])
  __shared__ int   s_lj[JR];    // 2 KB
  __shared__ int   s_last;
  __shared__ float ssm[4]; __shared__ unsigned snm[4];

  const int bi    = blockIdx.x >> 4;         // 0..63
  const int split = blockIdx.x & 15;         // 0..15
  const int i0    = bi * BI;
  const int jbase = split * JR;
  const int tid   = threadIdx.x;
  const int lane  = tid & 63;
  const int w     = tid >> 6;                // wave 0..3, owns rows [w*32, w*32+32)
  const int quad  = lane >> 4;
  const int l15   = lane & 15;

  // staging source offset: per kc, slot=tid -> row r=tid>>3 (0..31), group gs=tid&7, key r&7
  const int ssrc = (tid >> 3) * D_K + (((tid & 7) ^ ((tid >> 3) & 7)) << 3);

  // prologue stage: jt=0 -> buf 0 (4 async16/thread, one per kc chunk)
  {
    const ushort_t* gs_ = Ebf + (size_t)jbase * D_K + ssrc;
#pragma unroll
    for (int kc = 0; kc < 4; kc++)
      async16(gs_ + kc * 64, &Bs[0][kc][w * 512]);
  }

  for (int t = tid; t < JR; t += 256){ s_h2j[t] = C2F * sq[jbase + t]; s_lj[t] = labels[jbase + t]; }

  // A fragments: wave's 32 rows x K=256 (64 regs); per-lane resident i-row data (6 regs)
  bf16x8 af[2][8];
  float h2i_r[2]; int li_r[2], ji_r[2];
#pragma unroll
  for (int mt = 0; mt < 2; mt++){
    const int irow = i0 + w * 32 + mt * 16 + l15;
    const ushort_t* rp = Ebf + (size_t)irow * D_K + quad * 8;
#pragma unroll
    for (int c = 0; c < 8; c++)
      af[mt][c] = *reinterpret_cast<const bf16x8*>(rp + c * 32);
    h2i_r[mt] = C2F * sq[irow];
    li_r[mt]  = labels[irow];
    ji_r[mt]  = jsel[irow];
  }

  f32x4 acc[2][2];
#pragma unroll
  for (int mt = 0; mt < 2; mt++){ acc[mt][0] = (f32x4)0.f; acc[mt][1] = (f32x4)0.f; }
  float sm[2] = {NEG_INF, NEG_INF}, ssum[2] = {0.f, 0.f};

  __syncthreads();  // drains prologue stage (vmcnt0) + publishes s_h2j/s_lj

#pragma unroll 1
  for (int jt = 0; jt < NJT; jt++){
    const int b = jt & 1;
    if (jt + 1 < NJT){
      // stage next tile into the other buffer; counted wait leaves it in flight
      const ushort_t* gs_ = Ebf + (size_t)(jbase + (jt + 1) * BJ) * D_K + ssrc;
#pragma unroll
      for (int kc = 0; kc < 4; kc++)
        async16(gs_ + kc * 64, &Bs[b ^ 1][kc][w * 512]);
      asm volatile("s_waitcnt vmcnt(4)\n\ts_barrier" ::: "memory");
    } else {
      asm volatile("s_waitcnt vmcnt(0)\n\ts_barrier" ::: "memory");
    }

    // compute: 8 K-chunks; each bq feeds both A tiles. SWAPPED operands:
    // D = mfma(bq, af) -> C/D row = j (quad*4+rr), col = i (l15)
    __builtin_amdgcn_s_setprio(1);
#pragma unroll
    for (int c = 0; c < 8; c++){
      const int kc = c >> 1, g = (c & 1) * 4 + quad;
      bf16x8 bq[2];
#pragma unroll
      for (int q = 0; q < 2; q++){
        const int r = q * 16 + l15;
        bq[q] = *reinterpret_cast<const bf16x8*>(&Bs[b][kc][r * 64 + ((g ^ (r & 7)) << 3)]);
      }
#pragma unroll
      for (int q = 0; q < 2; q++){
        acc[0][q] = __builtin_amdgcn_mfma_f32_16x16x32_bf16(bq[q], af[0][c], acc[0][q], 0, 0, 0);
        acc[1][q] = __builtin_amdgcn_mfma_f32_16x16x32_bf16(bq[q], af[1][c], acc[1][q], 0, 0, 0);
      }
    }
    __builtin_amdgcn_s_setprio(0);

    // ---- epilogue: per lane, 2 i-rows x 8 j-vals; lse reduce is lane-local ----
    const int cb = jt * BJ;
#pragma unroll
    for (int mt = 0; mt < 2; mt++){
      float sv[8];
#pragma unroll
      for (int nt = 0; nt < 2; nt++){
        const f32x4 h2j4 = *reinterpret_cast<const f32x4*>(&s_h2j[cb + nt * 16 + quad * 4]);
        const int4  lj4  = *reinterpret_cast<const int4*>(&s_lj[cb + nt * 16 + quad * 4]);
        const int lj_[4] = {lj4.x, lj4.y, lj4.z, lj4.w};
        const int jg0 = jbase + cb + nt * 16 + quad * 4;
#pragma unroll
        for (int rr = 0; rr < 4; rr++){
          float a = acc[mt][nt][rr];
          float sim2 = fminf(fmaf(K2A, a, h2i_r[mt] + h2j4[rr]), 0.f);
          if (jg0 + rr == ji_r[mt]) numer[i0 + w * 32 + mt * 16 + l15] = sim2;
          sv[nt * 4 + rr] = (lj_[rr] != li_r[mt]) ? sim2 : NEG_INF;
        }
        acc[mt][nt] = (f32x4)0.f;
      }
      float m8 = fmaxf(fmaxf(fmaxf(sv[0],sv[1]),fmaxf(sv[2],sv[3])),
                       fmaxf(fmaxf(sv[4],sv[5]),fmaxf(sv[6],sv[7])));
      float s8 = ex2(sv[0]-m8)+ex2(sv[1]-m8)+ex2(sv[2]-m8)+ex2(sv[3]-m8)
               + ex2(sv[4]-m8)+ex2(sv[5]-m8)+ex2(sv[6]-m8)+ex2(sv[7]-m8);
      float M = fmaxf(sm[mt], m8);
      ssum[mt] = ssum[mt]*ex2(sm[mt]-M) + s8*ex2(m8-M);
      sm[mt] = M;
    }
    asm volatile("s_barrier" ::: "memory");  // Bs[b] readers done before it is restaged
  }

  // merge across the 4 quads (lanes l, l^16, l^32, l^48 share the i-row l15)
#pragma unroll
  for (int mt = 0; mt < 2; mt++){
    float mv = sm[mt], sv2 = ssum[mt];
#pragma unroll
    for (int mask = 16; mask < 64; mask <<= 1){
      float m2 = __shfl_xor(mv, mask);
      float s2 = __shfl_xor(sv2, mask);
      float M = fmaxf(mv, m2);
      sv2 = sv2 * ex2(mv - M) + s2 * ex2(m2 - M);
      mv = M;
    }
    if (quad == 0){
      int o = split * B_N + i0 + w * 32 + mt * 16 + l15;
      wsM[o] = mv; wsS[o] = sv2;
    }
  }

  // ---- last-block finale: device-scope fence + counter, one block reduces everything ----
  __threadfence();
  if (tid == 0){
    int old = atomicAdd((int*)&acc4[2], 1);
    s_last = (old == TOTB - 1) ? 1 : 0;
  }
  __syncthreads();
  if (s_last){
    __threadfence();
    float s_acc = 0.f; unsigned n_acc = 0u;
    for (int row = tid; row < B_N; row += 256){
      float M = -3.0e38f, S = 0.f;
#pragma unroll
      for (int p = 0; p < NPART; p++){
        float m2 = wsM[p * B_N + row], s2 = wsS[p * B_N + row];
        float Mn = fmaxf(M, m2);
        S = S * ex2(M - Mn) + s2 * ex2(m2 - Mn);
        M = Mn;
      }
      bool v = (jsel[row] >= 0) && (M > -5e29f);
      if (v){ s_acc += LN2F * (M + lg2(S) - numer[row]); n_acc += 1u; }
    }
#pragma unroll
    for (int off = 32; off > 0; off >>= 1){
      s_acc += __shfl_down(s_acc, off);
      n_acc += __shfl_down(n_acc, off);
    }
    if (lane == 0){ ssm[w] = s_acc; snm[w] = n_acc; }
    __syncthreads();
    if (tid == 0){
      float St = ssm[0] + ssm[1] + ssm[2] + ssm[3];
      unsigned Nt = snm[0] + snm[1] + snm[2] + snm[3];
      out[0] = (Nt > 0u) ? (St / (float)Nt) : 0.f;
    }
  }
}

extern "C" void kernel_launch(void* const* d_in, const int* in_sizes, int n_in,
                              void* d_out, int out_size, void* d_ws, size_t ws_size,
                              hipStream_t stream)
{
  const float* E      = (const float*)d_in[0];
  const int*   labels = (const int*)d_in[1];
  float*       out    = (float*)d_out;

  ushort_t* Ebf = (ushort_t*)d_ws;                     // 4 MB
  float* wsM    = (float*)(Ebf + (size_t)B_N * D_K);   // 512 KB (16 partials)
  float* wsS    = wsM + NPART * B_N;                   // 512 KB
  float* sqb    = wsS + NPART * B_N;                   // 32 KB
  float* numer  = sqb + B_N;                           // 32 KB
  int* jsel     = (int*)(numer + B_N);                 // 32 KB
  float* acc4   = (float*)(jsel + B_N);                // 16 B accumulators ([2] = done-counter)

  prep_kernel<<<B_N / 4 + NCLS * CPAR, 256, 0, stream>>>(E, Ebf, sqb, acc4, labels, jsel);
  fused_kernel<<<TOTB, 256, 0, stream>>>(Ebf, labels, sqb, jsel, numer, wsM, wsS, acc4, out);
}

// Round 9
// 181.593 us; speedup vs baseline: 1.3303x; 1.3303x over previous
//
#include <hip/hip_runtime.h>
#include <float.h>
#include <math.h>

// NPairLoss MI355X r16 = round-1 measured-best (133.57us, fused 62us) + minimal proven deltas:
//  - prep folds the wave-per-member gumbel argmax into the class blocks (round-4 proven)
//  - fused epilogue: drop never-binding fminf clamp; hoist numer check to per-rr target_nt
//  - separate 32-block finale kept (last-block-finale pattern implicated in r10/r15 collapses)
// THREE kernels: prep -> fused -> finale.

#define B_N 8192
#define D_K 256
#define NCLS 100
#define MAXC 512
#define NSPLIT 16
#define NPART NSPLIT
#define JR (B_N / NSPLIT)      // 512
#define BI 64
#define BJ 128
#define NJT (JR / BJ)          // 4
#define BK 64
#define NKC (D_K / BK)         // 4
#define NEG_INF -1e30f
#define C2F  (-14.426950408889634f)   // -10/T * log2(e)  (T=0.1)
#define K2A  (28.853900817779268f)    // +20 * log2(e)
#define LN2F (0.6931471805599453f)

typedef __attribute__((ext_vector_type(8))) short bf16x8;
typedef __attribute__((ext_vector_type(4))) float f32x4;
typedef unsigned short ushort_t;

__device__ __forceinline__ float ex2(float x){ return __builtin_amdgcn_exp2f(x); }
__device__ __forceinline__ float lg2(float x){ return __builtin_amdgcn_logf(x); }

// ---------------- threefry2x32 / jax gumbel (bit-exact, known-good) ----------------
__device__ __forceinline__ unsigned rotl32(unsigned x, int d){ return (x << d) | (x >> (32 - d)); }

__device__ __forceinline__ float gumbel_at(unsigned idx){
  const unsigned HALF = (unsigned)B_N * (unsigned)B_N / 2u;
  unsigned c0, c1; bool second;
  if (idx < HALF){ c0 = idx; c1 = idx + HALF; second = false; }
  else            { c0 = idx - HALF; c1 = idx; second = true; }
  const unsigned ks0 = 0u, ks1 = 42u, ks2 = 0u ^ 42u ^ 0x1BD11BDAu;
  unsigned x0 = c0 + ks0, x1 = c1 + ks1;
#define TF_RND(r) { x0 += x1; x1 = rotl32(x1, (r)); x1 ^= x0; }
  TF_RND(13) TF_RND(15) TF_RND(26) TF_RND(6)   x0 += ks1; x1 += ks2 + 1u;
  TF_RND(17) TF_RND(29) TF_RND(16) TF_RND(24)  x0 += ks2; x1 += ks0 + 2u;
  TF_RND(13) TF_RND(15) TF_RND(26) TF_RND(6)   x0 += ks0; x1 += ks1 + 3u;
  TF_RND(17) TF_RND(29) TF_RND(16) TF_RND(24)  x0 += ks1; x1 += ks2 + 4u;
  TF_RND(13) TF_RND(15) TF_RND(26) TF_RND(6)   x0 += ks2; x1 += ks0 + 5u;
#undef TF_RND
  unsigned bits = second ? x1 : x0;
  float u = __uint_as_float((bits >> 9) | 0x3f800000u) - 1.0f;
  const float TINY = 1.17549435e-38f;
  u = u * (1.0f - TINY) + TINY;
  u = fmaxf(TINY, u);
  return -logf(-logf(u));
}

__device__ __forceinline__ ushort_t f2bf(float x){
  unsigned u = __float_as_uint(x);
  return (ushort_t)((u + 0x7FFFu + ((u >> 16) & 1u)) >> 16); // RNE
}

__device__ __forceinline__ void async16(const ushort_t* g, ushort_t* lds_wave_base){
  __builtin_amdgcn_global_load_lds((const __attribute__((address_space(1))) void*)g,
                                   (__attribute__((address_space(3))) void*)lds_wave_base,
                                   16, 0, 0);
}

// ---------------- node 1. prep: convert + sq; class blocks build list + select jsel ----------------
__global__ __launch_bounds__(256)
void prep_kernel(const float* __restrict__ E, ushort_t* __restrict__ Ebf,
                 float* __restrict__ sq, float* __restrict__ acc4,
                 const int* __restrict__ labels, int* __restrict__ jsel){
  __shared__ int s_list[MAXC];
  __shared__ int s_n;
  if (blockIdx.x < B_N / 4){
    if (blockIdx.x == 0 && threadIdx.x < 4) acc4[threadIdx.x] = 0.f;
    int w = threadIdx.x >> 6, lane = threadIdx.x & 63;
    int row = blockIdx.x * 4 + w;
    const float4 v = *reinterpret_cast<const float4*>(E + (size_t)row * D_K + lane * 4);
    float s = v.x*v.x + v.y*v.y + v.z*v.z + v.w*v.w;
#pragma unroll
    for (int off = 32; off > 0; off >>= 1) s += __shfl_down(s, off);
    if (lane == 0) sq[row] = s;
    ushort4 o; o.x = f2bf(v.x); o.y = f2bf(v.y); o.z = f2bf(v.z); o.w = f2bf(v.w);
    *reinterpret_cast<ushort4*>(Ebf + (size_t)row * D_K + lane * 4) = o;
  } else {
    const int c = blockIdx.x - B_N / 4;
    const int tid = threadIdx.x;
    const int w = tid >> 6, lane = tid & 63;
    if (tid == 0) s_n = 0;
    __syncthreads();
    for (int t = tid; t < B_N; t += 256){
      if (labels[t] == c){
        int p = atomicAdd(&s_n, 1);
        if (p < MAXC) s_list[p] = t;
      }
    }
    __syncthreads();
    const int n = min(s_n, MAXC);
    // one WAVE per member: lane-parallel gumbel argmax over the class list (round-4 proven)
    for (int m = w; m < n; m += 4){
      const int row = s_list[m];
      float gb = -FLT_MAX; int jb = -1;
      for (int t = lane; t < n; t += 64){
        int j = s_list[t];
        if (j != row){
          float g = gumbel_at(((unsigned)row << 13) + (unsigned)j);
          if (g > gb || (g == gb && (unsigned)j < (unsigned)jb)){ gb = g; jb = j; }
        }
      }
#pragma unroll
      for (int off = 32; off > 0; off >>= 1){
        float g2 = __shfl_down(gb, off);
        int   j2 = __shfl_down(jb, off);
        if (g2 > gb || (g2 == gb && (unsigned)j2 < (unsigned)jb)){ gb = g2; jb = j2; }
      }
      if (lane == 0) jsel[row] = jb;
    }
  }
}

// ---------------- node 2. fused: ping-pong staged MFMA gram + exp2-domain online lse ----------------
__global__ __launch_bounds__(256)
void fused_kernel(const ushort_t* __restrict__ Ebf, const int* __restrict__ labels,
                  const float* __restrict__ sq, const int* __restrict__ jsel,
                  float* __restrict__ numer,
                  float* __restrict__ wsM, float* __restrict__ wsS)
{
  __shared__ __align__(16) ushort_t Bs[2][BJ * BK];  // 2 x 16 KB ping-pong, XOR-swizzled 16B groups
  __shared__ float s_h2j[JR];   // 2 KB  (= C2F * sq[j])
  __shared__ int   s_lj[JR];    // 2 KB
  __shared__ float s_h2i[BI];
  __shared__ int   s_li[BI];
  __shared__ int   s_ji[BI];

  const int bi    = blockIdx.x >> 4;         // 0..127
  const int split = blockIdx.x & 15;         // 0..15
  const int i0    = bi * BI;
  const int jbase = split * JR;
  const int tid   = threadIdx.x;
  const int lane  = tid & 63;
  const int w     = tid >> 6;                // wave 0..3, owns rows [w*16, w*16+16)
  const int quad  = lane >> 4;
  const int l15   = lane & 15;

  for (int t = tid; t < JR; t += 256){ s_h2j[t] = C2F * sq[jbase + t]; s_lj[t] = labels[jbase + t]; }
  if (tid < BI){ s_h2i[tid] = C2F * sq[i0 + tid]; s_li[tid] = labels[i0 + tid]; s_ji[tid] = jsel[i0 + tid]; }

  // A fragments: wave's 16 rows x K=256, register-resident (32 regs)
  bf16x8 af[8];
  {
    const ushort_t* rp = Ebf + (size_t)(i0 + w * 16 + l15) * D_K + quad * 8;
#pragma unroll
    for (int c = 0; c < 8; c++)
      af[c] = *reinterpret_cast<const bf16x8*>(rp + c * 32);
  }

  f32x4 acc[8];
#pragma unroll
  for (int nt = 0; nt < 8; nt++) acc[nt] = (f32x4)0.f;
  float sm[4], ssum[4];
#pragma unroll
  for (int r = 0; r < 4; r++){ sm[r] = NEG_INF; ssum[r] = 0.f; }

  // per-thread staging source offsets: slot = rd*256 + tid -> row r, pre-swizzled group
  int soff[4];
#pragma unroll
  for (int rd = 0; rd < 4; rd++){
    int slot = rd * 256 + tid;
    int r = slot >> 3, gs = slot & 7;
    soff[rd] = r * D_K + ((gs ^ (r & 7)) << 3);
  }

  // prologue: stage (jt=0,kc=0) into Bs[0]
#pragma unroll
  for (int rd = 0; rd < 4; rd++)
    async16(Ebf + (size_t)jbase * D_K + soff[rd],
            &Bs[0][(size_t)(rd * 256 + w * 64) * 8]);
  __syncthreads();  // drains prologue stage + publishes s_*

#pragma unroll 1
  for (int jt = 0; jt < NJT; jt++){
    const int j0 = jbase + jt * BJ;
#pragma unroll
    for (int kc = 0; kc < NKC; kc++){
      const int b = kc & 1;                  // NKC even -> parity restarts at 0 each jt
      // issue next step's stage into the other buffer (covered by this step's MFMA)
      const int sn = jt * NKC + kc + 1;
      if (sn < NJT * NKC){
        const int kcn = sn & 3;
        const size_t gb0 = (size_t)(jbase + (sn >> 2) * BJ) * D_K + (size_t)kcn * BK;
#pragma unroll
        for (int rd = 0; rd < 4; rd++)
          async16(Ebf + gb0 + soff[rd],
                  &Bs[b ^ 1][(size_t)(rd * 256 + w * 64) * 8]);
      }
      // compute current step from Bs[b]
#pragma unroll
      for (int s = 0; s < 2; s++){
        const int g = s * 4 + quad;          // k-group within 64-chunk
        const int c = kc * 2 + s;            // A-fragment chunk index
#pragma unroll
        for (int h = 0; h < 2; h++){         // nt in halves of 4 (caps live bfr at 16 regs)
          bf16x8 bfr[4];
#pragma unroll
          for (int q = 0; q < 4; q++){
            int r = (h * 4 + q) * 16 + l15;
            bfr[q] = *reinterpret_cast<const bf16x8*>(&Bs[b][r * BK + ((g ^ (r & 7)) << 3)]);
          }
#pragma unroll
          for (int q = 0; q < 4; q++)
            acc[h * 4 + q] = __builtin_amdgcn_mfma_f32_16x16x32_bf16(af[c], bfr[q], acc[h * 4 + q], 0, 0, 0);
        }
      }
      if (kc == NKC - 1){
        // ---- epilogue for this 128-col tile (log2-domain) ----
        float h2j[8]; int lj[8];
#pragma unroll
        for (int nt = 0; nt < 8; nt++){
          int ccol = jt * BJ + nt * 16 + l15;
          h2j[nt] = s_h2j[ccol]; lj[nt] = s_lj[ccol];
        }
#pragma unroll
        for (int rr = 0; rr < 4; rr++){
          const int rl = w * 16 + quad * 4 + rr;   // C/D: row = quad*4+reg, col = l15
          const float h2i = s_h2i[rl];
          const int lrow = s_li[rl], jsl = s_ji[rl];
          // hoisted numerator check: col jsl lives in this tile at nt = rel>>4 iff
          // rel = jsl - j0 - l15 in [0,128) with low 4 bits zero (col = j0 + nt*16 + l15)
          const int rel = jsl - j0 - l15;
          const int target_nt = ((unsigned)rel < 128u && (rel & 15) == 0) ? (rel >> 4) : -1;
          float sv[8];
#pragma unroll
          for (int nt = 0; nt < 8; nt++){
            float a = acc[nt][rr];
            // sim2 = log2e * sim = C2F*(sqi+sqj) + 20*log2e*a  (clamp at 0 never binds: dist2 ~ 512)
            float sim2 = fmaf(K2A, a, h2i + h2j[nt]);
            if (nt == target_nt) numer[i0 + rl] = sim2;   // rare predicated store
            sv[nt] = (lj[nt] != lrow) ? sim2 : NEG_INF;   // masks positives + same-label + diag
          }
          float m8 = fmaxf(fmaxf(fmaxf(sv[0],sv[1]),fmaxf(sv[2],sv[3])),
                           fmaxf(fmaxf(sv[4],sv[5]),fmaxf(sv[6],sv[7])));
          float s8 = ex2(sv[0]-m8)+ex2(sv[1]-m8)+ex2(sv[2]-m8)+ex2(sv[3]-m8)
                   + ex2(sv[4]-m8)+ex2(sv[5]-m8)+ex2(sv[6]-m8)+ex2(sv[7]-m8);
          float M = fmaxf(sm[rr], m8);
          ssum[rr] = ssum[rr]*ex2(sm[rr]-M) + s8*ex2(m8-M);
          sm[rr] = M;
        }
#pragma unroll
        for (int nt = 0; nt < 8; nt++) acc[nt] = (f32x4)0.f;
      }
      __syncthreads();  // drains the just-issued stage + protects Bs[b] for overwrite
    }
  }

  // merge the 16 l15-lanes sharing each row; rows wave-exclusive -> one slot per split
#pragma unroll
  for (int rr = 0; rr < 4; rr++){
    float mv = sm[rr], sv2 = ssum[rr];
#pragma unroll
    for (int mask = 1; mask < 16; mask <<= 1){
      float m2 = __shfl_xor(mv, mask);
      float s2 = __shfl_xor(sv2, mask);
      float M = fmaxf(mv, m2);
      sv2 = sv2 * ex2(mv - M) + s2 * ex2(m2 - M);
      mv = M;
    }
    if (l15 == 0){
      int rl = w * 16 + quad * 4 + rr;
      int o = split * B_N + i0 + rl;
      wsM[o] = mv; wsS[o] = sv2;
    }
  }
}

// ---------------- node 3. finale: 32 blocks, log2-domain merge, atomic finish ----------------
__global__ __launch_bounds__(256)
void finale_kernel(const float* __restrict__ wsM, const float* __restrict__ wsS,
                   const float* __restrict__ numer, const int* __restrict__ jsel,
                   float* __restrict__ acc4, float* __restrict__ out)
{
  const int tid = threadIdx.x;
  const int row = blockIdx.x * 256 + tid;   // 32*256 = 8192, one row per thread
  float M = -3.0e38f, S = 0.f;
#pragma unroll
  for (int p = 0; p < NPART; p++){
    float m2 = wsM[p * B_N + row], s2 = wsS[p * B_N + row];
    float Mn = fmaxf(M, m2);
    S = S * ex2(M - Mn) + s2 * ex2(m2 - Mn);
    M = Mn;
  }
  bool v = (jsel[row] >= 0) && (M > -5e29f);
  float s = v ? (LN2F * (M + lg2(S) - numer[row])) : 0.f;
  unsigned n = v ? 1u : 0u;
#pragma unroll
  for (int off = 32; off > 0; off >>= 1){ s += __shfl_down(s, off); n += __shfl_down(n, off); }
  __shared__ float ssm[4]; __shared__ unsigned snm[4];
  if ((tid & 63) == 0){ ssm[tid >> 6] = s; snm[tid >> 6] = n; }
  __syncthreads();
  if (tid == 0){
    float bs = ssm[0] + ssm[1] + ssm[2] + ssm[3];
    unsigned bn = snm[0] + snm[1] + snm[2] + snm[3];
    atomicAdd(&acc4[0], bs);
    atomicAdd((unsigned*)&acc4[1], bn);
    __threadfence();
    unsigned old = atomicAdd((unsigned*)&acc4[2], 1u);
    if (old == 31u){  // last block: publish
      float St = atomicAdd(&acc4[0], 0.f);
      unsigned Nt = atomicAdd((unsigned*)&acc4[1], 0u);
      out[0] = (Nt > 0u) ? (St / (float)Nt) : 0.f;
    }
  }
}

extern "C" void kernel_launch(void* const* d_in, const int* in_sizes, int n_in,
                              void* d_out, int out_size, void* d_ws, size_t ws_size,
                              hipStream_t stream)
{
  const float* E      = (const float*)d_in[0];
  const int*   labels = (const int*)d_in[1];
  float*       out    = (float*)d_out;

  ushort_t* Ebf = (ushort_t*)d_ws;                     // 4 MB
  float* wsM    = (float*)(Ebf + (size_t)B_N * D_K);   // 512 KB (16 partials)
  float* wsS    = wsM + NPART * B_N;                   // 512 KB
  float* sqb    = wsS + NPART * B_N;                   // 32 KB
  float* numer  = sqb + B_N;                           // 32 KB
  int* jsel     = (int*)(numer + B_N);                 // 32 KB
  float* acc4   = (float*)(jsel + B_N);                // 16 B accumulators

  prep_kernel<<<B_N / 4 + NCLS, 256, 0, stream>>>(E, Ebf, sqb, acc4, labels, jsel);
  fused_kernel<<<(B_N / BI) * NSPLIT, 256, 0, stream>>>(Ebf, labels, sqb, jsel, numer, wsM, wsS);
  finale_kernel<<<B_N / 256, 256, 0, stream>>>(wsM, wsS, numer, jsel, acc4, out);
}